// Round 1
// baseline (247.433 us; speedup 1.0000x reference)
//
#include <hip/hip_runtime.h>

#define NB 32

#if __has_builtin(__builtin_amdgcn_exp2f)
#define EXP2(x) __builtin_amdgcn_exp2f(x)
#else
#define EXP2(x) __expf((x) * 0.6931471805599453f)
#endif

// Main pass: each thread owns one anchor (b,m), accumulates 32 basis sums
// over an N-segment. Writes unnormalized partials to ws[seg][b*M+m][NB]
// (or, if applyNorm, normalized output directly when S==1).
__global__ __launch_bounds__(256) void gp_main(
    const float* __restrict__ f,
    const float* __restrict__ coords,
    const float* __restrict__ anchors,
    const float* __restrict__ gammas,
    const float* __restrict__ norms,
    float* __restrict__ ws,
    int B, int N, int M, int NSEG, int applyNorm)
{
    const int mtiles = M / 256;
    const int tile = blockIdx.x;          // over B * (M/256)
    const int seg  = blockIdx.y;          // N-segment
    const int b    = tile / mtiles;
    const int m    = (tile - b * mtiles) * 256 + threadIdx.x;
    const int bm   = b * M + m;

    const float ax = anchors[(size_t)bm * 3 + 0];
    const float ay = anchors[(size_t)bm * 3 + 1];
    const float az = anchors[(size_t)bm * 3 + 2];

    // -gamma_k * log2(e): uniform -> SGPRs after unroll
    float negc[NB];
#pragma unroll
    for (int k = 0; k < NB; ++k)
        negc[k] = -1.4426950408889634f * gammas[k];

    float acc[NB];
#pragma unroll
    for (int k = 0; k < NB; ++k) acc[k] = 0.0f;

    const float* __restrict__ fb = f + (size_t)b * N;
    const float* __restrict__ cb = coords + (size_t)b * N * 3;

    int n0 = seg * NSEG;
    int n1 = n0 + NSEG; if (n1 > N) n1 = N;

    for (int n = n0; n < n1; ++n) {
        // wave-uniform point data (scalar loads)
        const float px = cb[(size_t)n * 3 + 0];
        const float py = cb[(size_t)n * 3 + 1];
        const float pz = cb[(size_t)n * 3 + 2];
        const float fv = fb[n];

        const float dx = ax - px;
        const float dy = ay - py;
        const float dz = az - pz;
        const float d2 = fmaf(dx, dx, fmaf(dy, dy, dz * dz));

#pragma unroll
        for (int k = 0; k < NB; ++k) {
            const float e = EXP2(d2 * negc[k]);   // exp(-gamma_k * d2)
            acc[k] = fmaf(e, fv, acc[k]);
        }
    }

    float* __restrict__ w = ws + ((size_t)seg * (B * M) + bm) * NB;
    if (applyNorm) {
#pragma unroll
        for (int k = 0; k < NB; ++k) w[k] = acc[k] / norms[k];
    } else {
#pragma unroll
        for (int k = 0; k < NB; ++k) w[k] = acc[k];
    }
}

// Second pass: sum S partials and apply 1/norm. out[bm*NB + k].
__global__ __launch_bounds__(256) void gp_reduce(
    const float* __restrict__ ws,
    const float* __restrict__ norms,
    float* __restrict__ out,
    int BM, int S)
{
    const int t = blockIdx.x * blockDim.x + threadIdx.x;
    if (t >= BM * NB) return;
    const int k = t & (NB - 1);
    const size_t stride = (size_t)BM * NB;
    float s = 0.0f;
    for (int i = 0; i < S; ++i) s += ws[(size_t)i * stride + t];
    out[t] = s / norms[k];
}

extern "C" void kernel_launch(void* const* d_in, const int* in_sizes, int n_in,
                              void* d_out, int out_size, void* d_ws, size_t ws_size,
                              hipStream_t stream) {
    const float* f       = (const float*)d_in[0];
    const float* coords  = (const float*)d_in[1];
    const float* anchors = (const float*)d_in[2];
    const float* gammas  = (const float*)d_in[3];
    const float* norms   = (const float*)d_in[4];
    float* out = (float*)d_out;

    const int B = 2, N = 8192, M = 4096;
    const int BM = B * M;

    // Segments of N sized by workspace capacity (partials: S*BM*NB floats).
    int S = (int)(ws_size / ((size_t)BM * NB * sizeof(float)));
    if (S > 32) S = 32;
    int s2 = 1; while (s2 * 2 <= S) s2 *= 2;   // power of two dividing N
    S = (S >= 1) ? s2 : 0;

    if (S >= 2) {
        const int NSEG = N / S;
        dim3 grid(B * (M / 256), S);
        gp_main<<<grid, 256, 0, stream>>>(f, coords, anchors, gammas, norms,
                                          (float*)d_ws, B, N, M, NSEG, 0);
        const int total = BM * NB;
        gp_reduce<<<(total + 255) / 256, 256, 0, stream>>>(
            (const float*)d_ws, norms, out, BM, S);
    } else {
        // Workspace too small: single-segment, write normalized output directly.
        dim3 grid(B * (M / 256), 1);
        gp_main<<<grid, 256, 0, stream>>>(f, coords, anchors, gammas, norms,
                                          out, B, N, M, N, 1);
    }
}

// Round 2
// 216.700 us; speedup vs baseline: 1.1418x; 1.1418x over previous
//
#include <hip/hip_runtime.h>

#define NB 32
#define L2E 1.4426950408889634f

typedef float v2f __attribute__((ext_vector_type(2)));

#if __has_builtin(__builtin_amdgcn_exp2f)
#define EXP2(x) __builtin_amdgcn_exp2f(x)
#else
#define EXP2(x) __expf((x) * 0.6931471805599453f)
#endif

#if __has_builtin(__builtin_elementwise_fma)
#define VFMA(a, b, c) __builtin_elementwise_fma(a, b, c)
#else
static __device__ inline v2f VFMA(v2f a, v2f b, v2f c) {
    v2f r; r.x = fmaf(a.x, b.x, c.x); r.y = fmaf(a.y, b.y, c.y); return r;
}
#endif

// Main pass: block = (256 anchors) x (2 k-halves). Each thread owns one anchor
// (b,m) and 16 of the 32 basis functions (8 float2 pairs -> v_pk_* ops),
// accumulating over an N-segment. Partials to ws[seg][bm][NB] (or normalized
// output directly when S==1).
__global__ __launch_bounds__(512) void gp_main(
    const float* __restrict__ f,
    const float* __restrict__ coords,
    const float* __restrict__ anchors,
    const float* __restrict__ gammas,
    const float* __restrict__ norms,
    float* __restrict__ ws,
    int B, int N, int M, int NSEG, int applyNorm)
{
    const int mtiles = M / 256;
    const int tile = blockIdx.x;          // over B * (M/256)
    const int seg  = blockIdx.y;          // N-segment
    const int b    = tile / mtiles;
    const int m    = (tile - b * mtiles) * 256 + threadIdx.x;
    const int bm   = b * M + m;
    const int kh   = threadIdx.y;         // 0 or 1: which 16 bases
    const int kbase = kh * (NB / 2);

    const float ax = anchors[(size_t)bm * 3 + 0];
    const float ay = anchors[(size_t)bm * 3 + 1];
    const float az = anchors[(size_t)bm * 3 + 2];

    // -gamma_k * log2(e), paired for packed math (uniform -> SGPR pairs)
    v2f negc[NB / 4];
#pragma unroll
    for (int j = 0; j < NB / 4; ++j) {
        negc[j].x = -L2E * gammas[kbase + 2 * j + 0];
        negc[j].y = -L2E * gammas[kbase + 2 * j + 1];
    }

    v2f acc[NB / 4];
#pragma unroll
    for (int j = 0; j < NB / 4; ++j) acc[j] = (v2f)(0.0f);

    const float* __restrict__ fb = f + (size_t)b * N;
    const float* __restrict__ cb = coords + (size_t)b * N * 3;

    const int n0 = seg * NSEG;
    const int n1 = (n0 + NSEG > N) ? N : n0 + NSEG;

#pragma unroll 2
    for (int n = n0; n < n1; ++n) {
        // wave-uniform point data (scalar loads)
        const float px = cb[(size_t)n * 3 + 0];
        const float py = cb[(size_t)n * 3 + 1];
        const float pz = cb[(size_t)n * 3 + 2];
        const float fv = fb[n];

        const float dx = ax - px;
        const float dy = ay - py;
        const float dz = az - pz;
        const float d2 = fmaf(dx, dx, fmaf(dy, dy, dz * dz));
        const v2f d2v = (v2f)(d2);
        const v2f fvv = (v2f)(fv);

#pragma unroll
        for (int j = 0; j < NB / 4; ++j) {
            const v2f arg = d2v * negc[j];        // v_pk_mul_f32
            v2f e;
            e.x = EXP2(arg.x);                    // v_exp_f32
            e.y = EXP2(arg.y);
            acc[j] = VFMA(e, fvv, acc[j]);        // v_pk_fma_f32
        }
    }

    if (applyNorm) {
        float* __restrict__ w = ws + (size_t)bm * NB + kbase;
#pragma unroll
        for (int j = 0; j < NB / 4; ++j) {
            w[2 * j + 0] = acc[j].x / norms[kbase + 2 * j + 0];
            w[2 * j + 1] = acc[j].y / norms[kbase + 2 * j + 1];
        }
    } else {
        v2f* __restrict__ w = (v2f*)(ws + ((size_t)seg * (B * M) + bm) * NB + kbase);
#pragma unroll
        for (int j = 0; j < NB / 4; ++j) w[j] = acc[j];
    }
}

// Second pass: sum S partials (float4-vectorized) and apply 1/norm.
__global__ __launch_bounds__(256) void gp_reduce(
    const float4* __restrict__ ws,
    const float4* __restrict__ norms4,
    float4* __restrict__ out,
    int BM, int S)
{
    const int t = blockIdx.x * blockDim.x + threadIdx.x;   // over BM * NB/4
    if (t >= BM * (NB / 4)) return;
    const size_t stride = (size_t)BM * (NB / 4);
    float4 s = make_float4(0.f, 0.f, 0.f, 0.f);
    for (int i = 0; i < S; ++i) {
        const float4 v = ws[(size_t)i * stride + t];
        s.x += v.x; s.y += v.y; s.z += v.z; s.w += v.w;
    }
    const float4 nrm = norms4[t & (NB / 4 - 1)];
    s.x /= nrm.x; s.y /= nrm.y; s.z /= nrm.z; s.w /= nrm.w;
    out[t] = s;
}

extern "C" void kernel_launch(void* const* d_in, const int* in_sizes, int n_in,
                              void* d_out, int out_size, void* d_ws, size_t ws_size,
                              hipStream_t stream) {
    const float* f       = (const float*)d_in[0];
    const float* coords  = (const float*)d_in[1];
    const float* anchors = (const float*)d_in[2];
    const float* gammas  = (const float*)d_in[3];
    const float* norms   = (const float*)d_in[4];
    float* out = (float*)d_out;

    const int B = 2, N = 8192, M = 4096;
    const int BM = B * M;

    // Segments of N sized by workspace capacity (partials: S*BM*NB floats).
    int S = (int)(ws_size / ((size_t)BM * NB * sizeof(float)));
    if (S > 32) S = 32;
    int s2 = 1; while (s2 * 2 <= S) s2 *= 2;   // power of two dividing N
    S = (S >= 1) ? s2 : 0;

    dim3 block(256, 2);
    if (S >= 2) {
        const int NSEG = N / S;
        dim3 grid(B * (M / 256), S);
        gp_main<<<grid, block, 0, stream>>>(f, coords, anchors, gammas, norms,
                                            (float*)d_ws, B, N, M, NSEG, 0);
        const int total = BM * (NB / 4);
        gp_reduce<<<(total + 255) / 256, 256, 0, stream>>>(
            (const float4*)d_ws, (const float4*)norms, (float4*)out, BM, S);
    } else {
        dim3 grid(B * (M / 256), 1);
        gp_main<<<grid, block, 0, stream>>>(f, coords, anchors, gammas, norms,
                                            out, B, N, M, N, 1);
    }
}